// Round 1
// baseline (371.086 us; speedup 1.0000x reference)
//
#include <hip/hip_runtime.h>
#include <hip/hip_bf16.h>
#include <stdint.h>

typedef __attribute__((ext_vector_type(8))) short bf16x8;
typedef __attribute__((ext_vector_type(4))) short bf16x4;
typedef __attribute__((ext_vector_type(4))) float f32x4;

#define L2E 1.4426950408889634f

__device__ __forceinline__ unsigned short f2bf(float f) {
    __hip_bfloat16 h = __float2bfloat16(f);
    return __builtin_bit_cast(unsigned short, h);
}

__device__ __forceinline__ void gl2lds16(const void* g, void* l) {
    __builtin_amdgcn_global_load_lds(
        (const __attribute__((address_space(1))) void*)g,
        (__attribute__((address_space(3))) void*)l,
        16, 0, 0);
}

// ---------------- cast fp32 -> bf16 ----------------
__global__ void cast_kernel(const float* __restrict__ src,
                            unsigned short* __restrict__ dst, int n4) {
    int i = blockIdx.x * blockDim.x + threadIdx.x;
    int stride = gridDim.x * blockDim.x;
    for (; i < n4; i += stride) {
        float4 v = ((const float4*)src)[i];
        ushort4 o;
        o.x = f2bf(v.x); o.y = f2bf(v.y); o.z = f2bf(v.z); o.w = f2bf(v.w);
        ((ushort4*)dst)[i] = o;
    }
}

// ---------------- GEMM: C[i][j] = sum_k A[i][k] * W[j][k]  (torch Linear) ----
// A: [M][1024] bf16, W: [1024][1024] bf16, out = (acc + bias[j] (+bias2[j])) * scale
// M = 8192 (grid.y=64), N = 1024 (grid.x=8), K = 1024.
template<bool F32OUT>
__global__ __launch_bounds__(256) void gemm_bt(
    const unsigned short* __restrict__ A,
    const unsigned short* __restrict__ W,
    const float* __restrict__ bias,
    const float* __restrict__ bias2,
    float scale,
    unsigned short* __restrict__ obf,
    float* __restrict__ of)
{
    constexpr int K = 1024;
    __shared__ unsigned short As[128][64];
    __shared__ unsigned short Bs[128][64];

    const int tid  = threadIdx.x;
    const int wave = tid >> 6, lane = tid & 63;
    const int li = lane & 15, lg = lane >> 4;
    const int m0 = blockIdx.y * 128, n0 = blockIdx.x * 128;
    const int wm = (wave >> 1) * 64, wn = (wave & 1) * 64;

    const int srow = wave * 8 + (lane >> 3);   // row within a 32-row staging group
    const int scol = (lane & 7) * 8;           // col element (8 bf16 = 16B)

    f32x4 acc[4][4] = {};

    for (int k0 = 0; k0 < K; k0 += 64) {
#pragma unroll
        for (int rnd = 0; rnd < 4; ++rnd)
            gl2lds16(A + (size_t)(m0 + rnd * 32 + srow) * K + k0 + scol,
                     &As[rnd * 32 + wave * 8][0]);
#pragma unroll
        for (int rnd = 0; rnd < 4; ++rnd)
            gl2lds16(W + (size_t)(n0 + rnd * 32 + srow) * K + k0 + scol,
                     &Bs[rnd * 32 + wave * 8][0]);
        __syncthreads();
#pragma unroll
        for (int kk = 0; kk < 64; kk += 32) {
            bf16x8 af[4], bfr[4];
#pragma unroll
            for (int m = 0; m < 4; ++m)
                af[m] = *(const bf16x8*)&As[wm + m * 16 + li][kk + lg * 8];
#pragma unroll
            for (int n = 0; n < 4; ++n)
                bfr[n] = *(const bf16x8*)&Bs[wn + n * 16 + li][kk + lg * 8];
#pragma unroll
            for (int m = 0; m < 4; ++m)
#pragma unroll
                for (int n = 0; n < 4; ++n)
                    acc[m][n] = __builtin_amdgcn_mfma_f32_16x16x32_bf16(
                        af[m], bfr[n], acc[m][n], 0, 0, 0);
        }
        __syncthreads();
    }

#pragma unroll
    for (int n = 0; n < 4; ++n) {
        const int col = n0 + wn + n * 16 + li;
        float bb = bias[col];
        if (bias2) bb += bias2[col];
#pragma unroll
        for (int m = 0; m < 4; ++m) {
#pragma unroll
            for (int r = 0; r < 4; ++r) {
                const int row = m0 + wm + m * 16 + lg * 4 + r;
                float v = (acc[m][n][r] + bb) * scale;
                if (F32OUT) of[(size_t)row * 1024 + col] = v;
                else        obf[(size_t)row * 1024 + col] = f2bf(v);
            }
        }
    }
}

// ---------------- fused flash attention ----------------
// Q pre-scaled by (1/8)*log2(e); K,V raw. Band mask: +0.1*log2e if |i-j|<=2.
// Block: 4 waves, 64 q-rows (16 per wave). K-tiles of 64.
// Swapped QK^T: st = mfma(Kfrag, Qfrag) -> lane owns q-row i=lane&15,
// k-cols j = jf*16 + 4*(lane>>4) + reg.
__global__ __launch_bounds__(256) void attn_kernel(
    const unsigned short* __restrict__ Q,
    const unsigned short* __restrict__ Km,
    const unsigned short* __restrict__ Vm,
    unsigned short* __restrict__ AO)
{
    __shared__ unsigned short Ks[64][80];       // K rows (j) x d, padded
    __shared__ unsigned short Vt[64][80];       // V^T: d x j, padded
    __shared__ unsigned short Ps[4][16][80];    // per-wave P[i][j]

    const int tid  = threadIdx.x;
    const int wave = tid >> 6, lane = tid & 63;
    const int li = lane & 15, lg = lane >> 4;
    const int hb = blockIdx.y;                  // b*16 + h
    const int b = hb >> 4, h = hb & 15;
    const int q0 = blockIdx.x * 64;
    const size_t base = ((size_t)b * 2048) * 1024 + (size_t)h * 64;

    const int qrow = q0 + wave * 16 + li;       // this lane's q row in [0,2048)

    bf16x8 qf[2];
#pragma unroll
    for (int t = 0; t < 2; ++t)
        qf[t] = *(const bf16x8*)&Q[base + (size_t)qrow * 1024 + t * 32 + lg * 8];

    f32x4 acc[4] = {};                          // out^T d-blocks, col = q-row i
    float mrun = -INFINITY, lrun = 0.f;

    const int sr = tid >> 3;                    // staging row 0..31
    const int sc = (tid & 7) * 8;               // staging col element

    for (int j0 = 0; j0 < 2048; j0 += 64) {
        // stage K tile and V^T tile
#pragma unroll
        for (int it = 0; it < 2; ++it) {
            const int r = it * 32 + sr;
            int4 kv = *(const int4*)&Km[base + (size_t)(j0 + r) * 1024 + sc];
            *(int4*)&Ks[r][sc] = kv;
            int4 vv = *(const int4*)&Vm[base + (size_t)(j0 + r) * 1024 + sc];
            const unsigned short* u = (const unsigned short*)&vv;
#pragma unroll
            for (int e = 0; e < 8; ++e) Vt[sc + e][r] = u[e];
        }
        __syncthreads();

        // QK^T (swapped)
        f32x4 st[4];
#pragma unroll
        for (int jf = 0; jf < 4; ++jf) {
            bf16x8 kf0 = *(const bf16x8*)&Ks[jf * 16 + li][0 + lg * 8];
            bf16x8 kf1 = *(const bf16x8*)&Ks[jf * 16 + li][32 + lg * 8];
            f32x4 z = {};
            z = __builtin_amdgcn_mfma_f32_16x16x32_bf16(kf0, qf[0], z, 0, 0, 0);
            st[jf] = __builtin_amdgcn_mfma_f32_16x16x32_bf16(kf1, qf[1], z, 0, 0, 0);
        }

        // band mask (exp2 domain)
        if (j0 + 63 >= q0 - 2 && j0 <= q0 + 65) {
#pragma unroll
            for (int jf = 0; jf < 4; ++jf)
#pragma unroll
                for (int r = 0; r < 4; ++r) {
                    int jg = j0 + jf * 16 + lg * 4 + r;
                    int dq = qrow - jg;
                    if ((unsigned)(dq + 2) <= 4u) st[jf][r] += 0.1f * L2E;
                }
        }

        // online softmax (row i = li is lane-local; reduce over 4 lane-groups)
        float tm = st[0][0];
#pragma unroll
        for (int jf = 0; jf < 4; ++jf)
#pragma unroll
            for (int r = 0; r < 4; ++r) tm = fmaxf(tm, st[jf][r]);
        tm = fmaxf(tm, __shfl_xor(tm, 16));
        tm = fmaxf(tm, __shfl_xor(tm, 32));
        const float mnew = fmaxf(mrun, tm);
        const float rescale = exp2f(mrun - mnew);
        mrun = mnew;

        float psum = 0.f;
#pragma unroll
        for (int jf = 0; jf < 4; ++jf) {
            float p0 = exp2f(st[jf][0] - mnew);
            float p1 = exp2f(st[jf][1] - mnew);
            float p2 = exp2f(st[jf][2] - mnew);
            float p3 = exp2f(st[jf][3] - mnew);
            psum += (p0 + p1) + (p2 + p3);
            bf16x4 pk;
            pk[0] = (short)f2bf(p0); pk[1] = (short)f2bf(p1);
            pk[2] = (short)f2bf(p2); pk[3] = (short)f2bf(p3);
            *(bf16x4*)&Ps[wave][li][jf * 16 + lg * 4] = pk;
        }
        psum += __shfl_xor(psum, 16);
        psum += __shfl_xor(psum, 32);
        lrun = lrun * rescale + psum;

#pragma unroll
        for (int db = 0; db < 4; ++db)
#pragma unroll
            for (int r = 0; r < 4; ++r) acc[db][r] *= rescale;

        // PV: out^T += V^T x P^T
#pragma unroll
        for (int db = 0; db < 4; ++db) {
            bf16x8 vf0 = *(const bf16x8*)&Vt[db * 16 + li][0 + lg * 8];
            bf16x8 pf0 = *(const bf16x8*)&Ps[wave][li][0 + lg * 8];
            acc[db] = __builtin_amdgcn_mfma_f32_16x16x32_bf16(vf0, pf0, acc[db], 0, 0, 0);
            bf16x8 vf1 = *(const bf16x8*)&Vt[db * 16 + li][32 + lg * 8];
            bf16x8 pf1 = *(const bf16x8*)&Ps[wave][li][32 + lg * 8];
            acc[db] = __builtin_amdgcn_mfma_f32_16x16x32_bf16(vf1, pf1, acc[db], 0, 0, 0);
        }
        __syncthreads();
    }

    const float inv = 1.f / lrun;
#pragma unroll
    for (int db = 0; db < 4; ++db) {
        ushort4 o;
        o.x = f2bf(acc[db][0] * inv); o.y = f2bf(acc[db][1] * inv);
        o.z = f2bf(acc[db][2] * inv); o.w = f2bf(acc[db][3] * inv);
        *(ushort4*)&AO[base + (size_t)qrow * 1024 + db * 16 + lg * 4] = o;
    }
}

// ---------------- launch ----------------
extern "C" void kernel_launch(void* const* d_in, const int* in_sizes, int n_in,
                              void* d_out, int out_size, void* d_ws, size_t ws_size,
                              hipStream_t stream) {
    const float* x   = (const float*)d_in[0];
    // d_in[1] = ocr_context, unused (shape only in reference)
    const float* Wq  = (const float*)d_in[2];
    const float* bq  = (const float*)d_in[3];
    const float* Wk  = (const float*)d_in[4];
    const float* bk  = (const float*)d_in[5];
    const float* Wv  = (const float*)d_in[6];
    const float* bv  = (const float*)d_in[7];
    const float* Wo  = (const float*)d_in[8];
    const float* bo  = (const float*)d_in[9];
    const float* ocr = (const float*)d_in[10];
    float* out = (float*)d_out;

    char* ws = (char*)d_ws;
    const size_t MB = 1024 * 1024;
    unsigned short* xb  = (unsigned short*)(ws);            // 16 MB (reused as AO)
    unsigned short* Wqb = (unsigned short*)(ws + 16 * MB);  // 2 MB
    unsigned short* Wkb = (unsigned short*)(ws + 18 * MB);
    unsigned short* Wvb = (unsigned short*)(ws + 20 * MB);
    unsigned short* Wob = (unsigned short*)(ws + 22 * MB);
    unsigned short* Qb  = (unsigned short*)(ws + 24 * MB);  // 16 MB
    unsigned short* Kb  = (unsigned short*)(ws + 40 * MB);  // 16 MB
    unsigned short* Vb  = (unsigned short*)(ws + 56 * MB);  // 16 MB
    unsigned short* AO  = xb;  // x dead after projections

    cast_kernel<<<2048, 256, 0, stream>>>(x,  xb,  8388608 / 4);
    cast_kernel<<<512,  256, 0, stream>>>(Wq, Wqb, 1048576 / 4);
    cast_kernel<<<512,  256, 0, stream>>>(Wk, Wkb, 1048576 / 4);
    cast_kernel<<<512,  256, 0, stream>>>(Wv, Wvb, 1048576 / 4);
    cast_kernel<<<512,  256, 0, stream>>>(Wo, Wob, 1048576 / 4);

    dim3 g(8, 64);
    const float QSC = 0.125f * L2E;  // fold 1/sqrt(64) and log2(e) into Q
    gemm_bt<false><<<g, 256, 0, stream>>>(xb, Wqb, bq, ocr,      QSC, Qb, nullptr);
    gemm_bt<false><<<g, 256, 0, stream>>>(xb, Wkb, bk, nullptr,  1.f, Kb, nullptr);
    gemm_bt<false><<<g, 256, 0, stream>>>(xb, Wvb, bv, nullptr,  1.f, Vb, nullptr);

    attn_kernel<<<dim3(32, 64), 256, 0, stream>>>(Qb, Kb, Vb, AO);

    gemm_bt<true><<<g, 256, 0, stream>>>(AO, Wob, bo, nullptr, 1.f, nullptr, out);
}

// Round 2
// 229.532 us; speedup vs baseline: 1.6167x; 1.6167x over previous
//
#include <hip/hip_runtime.h>
#include <hip/hip_bf16.h>
#include <stdint.h>

typedef __attribute__((ext_vector_type(8))) short bf16x8;
typedef __attribute__((ext_vector_type(4))) short bf16x4;
typedef __attribute__((ext_vector_type(4))) float f32x4;

#define L2E 1.4426950408889634f

static __device__ __forceinline__ unsigned short f2bf(float f) {
    __hip_bfloat16 h = __float2bfloat16(f);
    return __builtin_bit_cast(unsigned short, h);
}

static __device__ __forceinline__ void gl2lds16(const void* g, void* l) {
    __builtin_amdgcn_global_load_lds(
        (const __attribute__((address_space(1))) void*)g,
        (__attribute__((address_space(3))) void*)l,
        16, 0, 0);
}

// ---------------- cast fp32 -> bf16 ----------------
__global__ void cast_kernel(const float* __restrict__ src,
                            unsigned short* __restrict__ dst, int n4) {
    int i = blockIdx.x * blockDim.x + threadIdx.x;
    int stride = gridDim.x * blockDim.x;
    for (; i < n4; i += stride) {
        float4 v = ((const float4*)src)[i];
        ushort4 o;
        o.x = f2bf(v.x); o.y = f2bf(v.y); o.z = f2bf(v.z); o.w = f2bf(v.w);
        ((ushort4*)dst)[i] = o;
    }
}

// ---------------- GEMM: C[i][j] = sum_k A[i][k] * W[j][k]  (torch Linear) ----
// OM: 0 = bf16 row-major, 1 = f32 row-major, 2 = bf16 transposed V^T [bh][d][s]
template<int OM>
__global__ __launch_bounds__(256) void gemm_bt(
    const unsigned short* __restrict__ A,
    const unsigned short* __restrict__ W,
    const float* __restrict__ bias,
    const float* __restrict__ bias2,
    float scale,
    unsigned short* __restrict__ obf,
    float* __restrict__ of)
{
    constexpr int K = 1024;
    __shared__ unsigned short As[128][64];
    __shared__ unsigned short Bs[128][64];

    const int tid  = threadIdx.x;
    const int wave = tid >> 6, lane = tid & 63;
    const int li = lane & 15, lg = lane >> 4;
    const int m0 = blockIdx.y * 128, n0 = blockIdx.x * 128;
    const int wm = (wave >> 1) * 64, wn = (wave & 1) * 64;

    const int srow = wave * 8 + (lane >> 3);
    const int scol = (lane & 7) * 8;

    f32x4 acc[4][4] = {};

    for (int k0 = 0; k0 < K; k0 += 64) {
#pragma unroll
        for (int rnd = 0; rnd < 4; ++rnd)
            gl2lds16(A + (size_t)(m0 + rnd * 32 + srow) * K + k0 + scol,
                     &As[rnd * 32 + wave * 8][0]);
#pragma unroll
        for (int rnd = 0; rnd < 4; ++rnd)
            gl2lds16(W + (size_t)(n0 + rnd * 32 + srow) * K + k0 + scol,
                     &Bs[rnd * 32 + wave * 8][0]);
        __syncthreads();
#pragma unroll
        for (int kk = 0; kk < 64; kk += 32) {
            bf16x8 af[4], bfr[4];
#pragma unroll
            for (int m = 0; m < 4; ++m)
                af[m] = *(const bf16x8*)&As[wm + m * 16 + li][kk + lg * 8];
#pragma unroll
            for (int n = 0; n < 4; ++n)
                bfr[n] = *(const bf16x8*)&Bs[wn + n * 16 + li][kk + lg * 8];
#pragma unroll
            for (int m = 0; m < 4; ++m)
#pragma unroll
                for (int n = 0; n < 4; ++n)
                    acc[m][n] = __builtin_amdgcn_mfma_f32_16x16x32_bf16(
                        af[m], bfr[n], acc[m][n], 0, 0, 0);
        }
        __syncthreads();
    }

#pragma unroll
    for (int n = 0; n < 4; ++n) {
        const int col = n0 + wn + n * 16 + li;
        float bb = bias[col];
        if (bias2) bb += bias2[col];
#pragma unroll
        for (int m = 0; m < 4; ++m) {
            if (OM == 2) {
                const int row0 = m0 + wm + m * 16 + lg * 4;
                // V^T layout: [bh][d][s], bh = (row0>>11)*16 + col>>6, d = col&63, s = row0&2047 (+r)
                size_t addr = ((size_t)(((row0 >> 11) << 4) + (col >> 6)) * 64 + (col & 63)) * 2048
                              + (row0 & 2047);
                ushort4 o;
                o.x = f2bf((acc[m][n][0] + bb) * scale);
                o.y = f2bf((acc[m][n][1] + bb) * scale);
                o.z = f2bf((acc[m][n][2] + bb) * scale);
                o.w = f2bf((acc[m][n][3] + bb) * scale);
                *(ushort4*)&obf[addr] = o;
            } else {
#pragma unroll
                for (int r = 0; r < 4; ++r) {
                    const int row = m0 + wm + m * 16 + lg * 4 + r;
                    float v = (acc[m][n][r] + bb) * scale;
                    if (OM == 1) of[(size_t)row * 1024 + col] = v;
                    else         obf[(size_t)row * 1024 + col] = f2bf(v);
                }
            }
        }
    }
}

// ---------------- fused flash attention ----------------
// Q pre-scaled by (1/8)*log2(e). No max-subtraction (scores bounded; softmax
// is shift-invariant). 4 waves x 2 q-sets x 16 rows = 128 q-rows per block.
// K and V^T staged via global_load_lds with XOR-swizzled global source
// (LDS[row][ch] = G[row][ch ^ (row&7)], 16B chunks) -> conflict-free b128 reads.
__global__ __launch_bounds__(256, 3) void attn_kernel(
    const unsigned short* __restrict__ Q,
    const unsigned short* __restrict__ Km,
    const unsigned short* __restrict__ VT,
    unsigned short* __restrict__ AO)
{
    __shared__ unsigned short Ks[2][4096];      // [buf][64 j][64 d] swizzled
    __shared__ unsigned short Vs[2][4096];      // [buf][64 d][64 j] swizzled
    __shared__ unsigned short Ps[2][4][1024];   // [set][wave][16 i][64 j] swizzled

    const int tid  = threadIdx.x;
    const int w = tid >> 6, lane = tid & 63;
    const int li = lane & 15, lg = lane >> 4, li7 = li & 7;

    // XCD-chunked swizzle over 1024 blocks (16 x 64 grid)
    const int p  = blockIdx.y * 16 + blockIdx.x;
    const int q_ = (p & 7) * 128 + (p >> 3);
    const int bx = q_ & 15, bh = q_ >> 4;
    const int b = bh >> 4, h = bh & 15;
    const int q0 = bx * 128;
    const int qb0 = q0 + w * 32;                // set0 base; set1 = +16

    // staging constants: row = srow + it*8, swizzled chunk source
    const int srow = w * 16 + (lane >> 3);
    const int swz  = ((lane & 7) ^ (lane >> 3)) * 8;

    const unsigned short* Kg0 = Km + (size_t)(b * 2048 + srow) * 1024 + h * 64 + swz;
    const unsigned short* Vg0 = VT + ((size_t)bh * 64 + srow) * 2048 + swz;

    bf16x8 qf[2][2];
#pragma unroll
    for (int s = 0; s < 2; ++s)
#pragma unroll
        for (int t = 0; t < 2; ++t)
            qf[s][t] = *(const bf16x8*)&Q[(size_t)(b * 2048 + qb0 + s * 16 + li) * 1024
                                          + h * 64 + t * 32 + lg * 8];

    f32x4 acc[2][4] = {};
    float lr[2] = {0.f, 0.f};

    // prologue: stage tile 0 into buf 0
#pragma unroll
    for (int it = 0; it < 2; ++it) {
        gl2lds16(Kg0 + (size_t)(it * 8) * 1024, &Ks[0][(w * 2 + it) * 512]);
        gl2lds16(Vg0 + (size_t)(it * 8) * 2048, &Vs[0][(w * 2 + it) * 512]);
    }
    __syncthreads();

    for (int t = 0; t < 32; ++t) {
        const int buf = t & 1;
        const int j0 = t * 64;
        if (t < 31) {
            const int j1 = j0 + 64;
#pragma unroll
            for (int it = 0; it < 2; ++it) {
                gl2lds16(Kg0 + (size_t)(j1 + it * 8) * 1024, &Ks[buf ^ 1][(w * 2 + it) * 512]);
                gl2lds16(Vg0 + (size_t)(it * 8) * 2048 + j1, &Vs[buf ^ 1][(w * 2 + it) * 512]);
            }
        }

        // K fragments (shared across both q-sets)
        bf16x8 kf[2][4];
#pragma unroll
        for (int tt = 0; tt < 2; ++tt)
#pragma unroll
            for (int jf = 0; jf < 4; ++jf)
                kf[tt][jf] = *(const bf16x8*)&Ks[buf][(jf * 16 + li) * 64
                                                      + ((tt * 4 + lg) ^ li7) * 8];

        // QK^T + softmax per set
#pragma unroll
        for (int s = 0; s < 2; ++s) {
            f32x4 st[4];
#pragma unroll
            for (int jf = 0; jf < 4; ++jf) {
                f32x4 z = {};
                z = __builtin_amdgcn_mfma_f32_16x16x32_bf16(kf[0][jf], qf[s][0], z, 0, 0, 0);
                st[jf] = __builtin_amdgcn_mfma_f32_16x16x32_bf16(kf[1][jf], qf[s][1], z, 0, 0, 0);
            }
            const int qb = qb0 + s * 16;
            if (j0 + 65 >= qb && j0 <= qb + 17) {
#pragma unroll
                for (int jf = 0; jf < 4; ++jf)
#pragma unroll
                    for (int r = 0; r < 4; ++r) {
                        int dq = (qb + li) - (j0 + jf * 16 + lg * 4 + r);
                        if ((unsigned)(dq + 2) <= 4u) st[jf][r] += 0.1f * L2E;
                    }
            }
            float ps = 0.f;
#pragma unroll
            for (int jf = 0; jf < 4; ++jf) {
                float p0 = __builtin_amdgcn_exp2f(st[jf][0]);
                float p1 = __builtin_amdgcn_exp2f(st[jf][1]);
                float p2 = __builtin_amdgcn_exp2f(st[jf][2]);
                float p3 = __builtin_amdgcn_exp2f(st[jf][3]);
                ps += (p0 + p1) + (p2 + p3);
                bf16x4 pk;
                pk[0] = (short)f2bf(p0); pk[1] = (short)f2bf(p1);
                pk[2] = (short)f2bf(p2); pk[3] = (short)f2bf(p3);
                *(bf16x4*)&Ps[s][w][li * 64 + ((jf * 2 + (lg >> 1)) ^ li7) * 8
                                    + (lg & 1) * 4] = pk;
            }
            lr[s] += ps;
        }

        // V fragments (shared across sets) + PV
        bf16x8 vf[2][4];
#pragma unroll
        for (int tt = 0; tt < 2; ++tt)
#pragma unroll
            for (int db = 0; db < 4; ++db)
                vf[tt][db] = *(const bf16x8*)&Vs[buf][(db * 16 + li) * 64
                                                      + ((tt * 4 + lg) ^ li7) * 8];
#pragma unroll
        for (int s = 0; s < 2; ++s) {
            bf16x8 pf0 = *(const bf16x8*)&Ps[s][w][li * 64 + ((0 + lg) ^ li7) * 8];
            bf16x8 pf1 = *(const bf16x8*)&Ps[s][w][li * 64 + ((4 + lg) ^ li7) * 8];
#pragma unroll
            for (int db = 0; db < 4; ++db) {
                acc[s][db] = __builtin_amdgcn_mfma_f32_16x16x32_bf16(vf[0][db], pf0, acc[s][db], 0, 0, 0);
                acc[s][db] = __builtin_amdgcn_mfma_f32_16x16x32_bf16(vf[1][db], pf1, acc[s][db], 0, 0, 0);
            }
        }
        __syncthreads();
    }

#pragma unroll
    for (int s = 0; s < 2; ++s) {
        float l2 = lr[s] + __shfl_xor(lr[s], 16);
        l2 += __shfl_xor(l2, 32);
        const float inv = 1.f / l2;
#pragma unroll
        for (int db = 0; db < 4; ++db) {
            ushort4 o;
            o.x = f2bf(acc[s][db][0] * inv); o.y = f2bf(acc[s][db][1] * inv);
            o.z = f2bf(acc[s][db][2] * inv); o.w = f2bf(acc[s][db][3] * inv);
            *(ushort4*)&AO[(size_t)(b * 2048 + qb0 + s * 16 + li) * 1024
                           + h * 64 + db * 16 + lg * 4] = o;
        }
    }
}

// ---------------- launch ----------------
extern "C" void kernel_launch(void* const* d_in, const int* in_sizes, int n_in,
                              void* d_out, int out_size, void* d_ws, size_t ws_size,
                              hipStream_t stream) {
    const float* x   = (const float*)d_in[0];
    const float* Wq  = (const float*)d_in[2];
    const float* bq  = (const float*)d_in[3];
    const float* Wk  = (const float*)d_in[4];
    const float* bk  = (const float*)d_in[5];
    const float* Wv  = (const float*)d_in[6];
    const float* bv  = (const float*)d_in[7];
    const float* Wo  = (const float*)d_in[8];
    const float* bo  = (const float*)d_in[9];
    const float* ocr = (const float*)d_in[10];
    float* out = (float*)d_out;

    char* ws = (char*)d_ws;
    const size_t MB = 1024 * 1024;
    unsigned short* xb  = (unsigned short*)(ws);            // 16 MB (reused as AO)
    unsigned short* Wqb = (unsigned short*)(ws + 16 * MB);  // 2 MB each
    unsigned short* Wkb = (unsigned short*)(ws + 18 * MB);
    unsigned short* Wvb = (unsigned short*)(ws + 20 * MB);
    unsigned short* Wob = (unsigned short*)(ws + 22 * MB);
    unsigned short* Qb  = (unsigned short*)(ws + 24 * MB);  // 16 MB
    unsigned short* Kb  = (unsigned short*)(ws + 40 * MB);  // 16 MB
    unsigned short* VTb = (unsigned short*)(ws + 56 * MB);  // 16 MB, [bh][d][s]
    unsigned short* AO  = xb;  // x dead after projections

    cast_kernel<<<2048, 256, 0, stream>>>(x,  xb,  8388608 / 4);
    cast_kernel<<<512,  256, 0, stream>>>(Wq, Wqb, 1048576 / 4);
    cast_kernel<<<512,  256, 0, stream>>>(Wk, Wkb, 1048576 / 4);
    cast_kernel<<<512,  256, 0, stream>>>(Wv, Wvb, 1048576 / 4);
    cast_kernel<<<512,  256, 0, stream>>>(Wo, Wob, 1048576 / 4);

    dim3 g(8, 64);
    const float QSC = 0.125f * L2E;  // fold 1/sqrt(64) and log2(e) into Q
    gemm_bt<0><<<g, 256, 0, stream>>>(xb, Wqb, bq, ocr,     QSC, Qb,  nullptr);
    gemm_bt<0><<<g, 256, 0, stream>>>(xb, Wkb, bk, nullptr, 1.f, Kb,  nullptr);
    gemm_bt<2><<<g, 256, 0, stream>>>(xb, Wvb, bv, nullptr, 1.f, VTb, nullptr);

    attn_kernel<<<dim3(16, 64), 256, 0, stream>>>(Qb, Kb, VTb, AO);

    gemm_bt<1><<<g, 256, 0, stream>>>(AO, Wob, bo, nullptr, 1.f, nullptr, out);
}